// Round 9
// baseline (291.461 us; speedup 1.0000x reference)
//
#include <hip/hip_runtime.h>
#include <hip/hip_bf16.h>

#define BATCH 65536
#define DIN   128
#define DH    512
#define DOUT  128
#define ROWS  32

typedef __attribute__((ext_vector_type(4))) float f32x4;
typedef __attribute__((ext_vector_type(8))) short s16x8;

__device__ __forceinline__ ushort f32_to_bf16_rn(float f) {
    uint32_t u = __float_as_uint(f);
    uint32_t r = (u + 0x7FFFu + ((u >> 16) & 1u)) >> 16;
    return (ushort)r;
}
__device__ __forceinline__ float bf16_to_f32(ushort h) {
    return __uint_as_float(((uint32_t)h) << 16);
}
__device__ __forceinline__ f32x4 mfma16(s16x8 a, s16x8 b, f32x4 c) {
    return __builtin_amdgcn_mfma_f32_16x16x32_bf16(a, b, c, 0, 0, 0);
}

struct Split8 { s16x8 h, l; };
__device__ __forceinline__ Split8 split8(f32x4 v0, f32x4 v1) {
    Split8 s;
#pragma unroll
    for (int j = 0; j < 4; ++j) {
        ushort hh = f32_to_bf16_rn(v0[j]);
        s.h[j] = (short)hh;
        s.l[j] = (short)f32_to_bf16_rn(v0[j] - bf16_to_f32(hh));
    }
#pragma unroll
    for (int j = 0; j < 4; ++j) {
        ushort hh = f32_to_bf16_rn(v1[j]);
        s.h[4 + j] = (short)hh;
        s.l[4 + j] = (short)f32_to_bf16_rn(v1[j] - bf16_to_f32(hh));
    }
    return s;
}

// ---------------------------------------------------------------------------
// prep1: blk0 softmax; blk1..64 B/C split (verified layout); blk65..128
// bc_f32 = b @ c ([128][128] f32, coalesced on c).
// Fragment-linear layout: perm[(f*64+lane)*8+j] = M[k][col],
// k = ks*32+(lane>>4)*8+j, col = cg*16+(lane&15).
// B: f=cg*4+ks (cg<32). C: f=cg*16+ksg (cg<8, ksg<16).
// ---------------------------------------------------------------------------
__global__ void prep1_kernel(const float* __restrict__ a,
                             const float* __restrict__ b,
                             const float* __restrict__ c,
                             float* __restrict__ decay,
                             ushort* __restrict__ bhi, ushort* __restrict__ blo,
                             ushort* __restrict__ chi, ushort* __restrict__ clo,
                             float* __restrict__ bcf)
{
    const int t = threadIdx.x;
    if (blockIdx.x == 0) {
        __shared__ float red[256];
        float v0 = a[t], v1 = a[t + 256];
        red[t] = fmaxf(v0, v1);
        __syncthreads();
        for (int s = 128; s > 0; s >>= 1) {
            if (t < s) red[t] = fmaxf(red[t], red[t + s]);
            __syncthreads();
        }
        float M = red[0];
        __syncthreads();
        float e0 = expf(v0 - M), e1 = expf(v1 - M);
        red[t] = e0 + e1;
        __syncthreads();
        for (int s = 128; s > 0; s >>= 1) {
            if (t < s) red[t] += red[t + s];
            __syncthreads();
        }
        float S = red[0];
        decay[t]       = e0 / S;
        decay[t + 256] = e1 / S;
    } else if (blockIdx.x <= 64) {
        const int p = (blockIdx.x - 1) * 256 + t;
        const int mtx = p >> 13;
        const int q = p & 8191;
        const int f = q >> 6;
        const int l = q & 63;
        s16x8 hi, lo;
        if (mtx == 0) {
            const int cg = f >> 2, ks = f & 3;
            const int col = cg * 16 + (l & 15);
            const int kbase = ks * 32 + (l >> 4) * 8;
#pragma unroll
            for (int j = 0; j < 8; ++j) {
                float v = b[(size_t)(kbase + j) * DH + col];
                ushort h = f32_to_bf16_rn(v);
                hi[j] = (short)h;
                lo[j] = (short)f32_to_bf16_rn(v - bf16_to_f32(h));
            }
            *(s16x8*)(bhi + (size_t)q * 8) = hi;
            *(s16x8*)(blo + (size_t)q * 8) = lo;
        } else {
            const int cg = f >> 4, ks = f & 15;
            const int col = cg * 16 + (l & 15);
            const int kbase = ks * 32 + (l >> 4) * 8;
#pragma unroll
            for (int j = 0; j < 8; ++j) {
                float v = c[(size_t)(kbase + j) * DOUT + col];
                ushort h = f32_to_bf16_rn(v);
                hi[j] = (short)h;
                lo[j] = (short)f32_to_bf16_rn(v - bf16_to_f32(h));
            }
            *(s16x8*)(chi + (size_t)q * 8) = hi;
            *(s16x8*)(clo + (size_t)q * 8) = lo;
        }
    } else {
        // bc = b @ c (f32). One output per thread; c reads coalesced.
        const int i = (blockIdx.x - 65) * 2 + (t >> 7);
        const int j = t & 127;
        float acc = 0.f;
        for (int k = 0; k < DH; ++k)
            acc = fmaf(b[(size_t)i * DH + k], c[(size_t)k * DOUT + j], acc);
        bcf[i * DOUT + j] = acc;
    }
}

// ---------------------------------------------------------------------------
// prep2: split bc_f32 into frag-linear hi/lo (K=128: f = cg*4+ks, cg<8).
// ---------------------------------------------------------------------------
__global__ void prep2_kernel(const float* __restrict__ bcf,
                             ushort* __restrict__ bch, ushort* __restrict__ bcl)
{
    const int p = blockIdx.x * 256 + threadIdx.x;   // [0, 2048)
    const int f = p >> 6, l = p & 63;
    const int cg = f >> 2, ks = f & 3;
    const int col = cg * 16 + (l & 15);
    const int kbase = ks * 32 + (l >> 4) * 8;
    s16x8 hi, lo;
#pragma unroll
    for (int j = 0; j < 8; ++j) {
        float v = bcf[(size_t)(kbase + j) * DOUT + col];
        ushort h = f32_to_bf16_rn(v);
        hi[j] = (short)h;
        lo[j] = (short)f32_to_bf16_rn(v - bf16_to_f32(h));
    }
    *(s16x8*)(bch + (size_t)p * 8) = hi;
    *(s16x8*)(bcl + (size_t)p * 8) = lo;
}

// ---------------------------------------------------------------------------
// fused v5: zero main-loop barriers, no X LDS.
//   out = (decay*x)@c + u@bc ; xn = u@b + decay*x.
// Block 32 rows, 4 waves. A = u staged once in LDS (16KB). Per 64-col chunk:
//   GEMM1 (u@B, wave cols (ct*4+w)*16, 24 MFMA, B-frags L2)
//   xn store = acc1 + dv*x (x loaded C/D layout, 16 dwords)
//   GEMM2: X-frags = split(decay*x) built IN REGISTERS from x A-frag-layout
//          loads (32B/lane, L2-hot second touch) -> 24 MFMA vs C-frags.
// Final: acc2 += u@bc (48 MFMA), store out. Waves drift independently.
// ---------------------------------------------------------------------------
__global__ __launch_bounds__(256, 4)
void rnn_fused(const float* __restrict__ u, const float* __restrict__ x,
               const float* __restrict__ decay,
               const ushort* __restrict__ bhi, const ushort* __restrict__ blo,
               const ushort* __restrict__ chi, const ushort* __restrict__ clo,
               const ushort* __restrict__ bch, const ushort* __restrict__ bcl,
               float* __restrict__ xn, float* __restrict__ out)
{
    __shared__ __align__(16) char smem[16384];
    ushort* Ah = (ushort*)smem;              // [32][128] bf16 hi, swz, 8KB
    ushort* Al = (ushort*)(smem + 8192);

    const int t = threadIdx.x;
    const int lane = t & 63, w = t >> 6;
    const int cl = lane & 15, hk = lane >> 4;
    const int row0 = blockIdx.x * ROWS;

    {   // stage A: u[32][128] f32 -> hi/lo bf16 swizzled, coalesced
        const int r = t >> 3;
        const int kb = (t & 7) * 2;
#pragma unroll
        for (int i = 0; i < 2; ++i) {
            const float* src = u + (size_t)(row0 + r) * DIN + (kb + i) * 8;
            f32x4 v0 = *(const f32x4*)src;
            f32x4 v1 = *(const f32x4*)(src + 4);
            Split8 s = split8(v0, v1);
            const int byte = (r * 256 + (kb + i) * 16) ^ ((r & 7) << 4);
            *(s16x8*)((char*)Ah + byte) = s.h;
            *(s16x8*)((char*)Al + byte) = s.l;
        }
    }
    __syncthreads();   // the only block-wide barrier

    f32x4 acc2[2][2];
#pragma unroll
    for (int mf = 0; mf < 2; ++mf)
#pragma unroll
        for (int nf = 0; nf < 2; ++nf)
            acc2[mf][nf] = (f32x4){0.f, 0.f, 0.f, 0.f};

    for (int ct = 0; ct < 8; ++ct) {
        // ---- x (C/D layout) + decay for the xn epilogue; hides under GEMM1
        const int col = ct * 64 + w * 16 + cl;
        const float dvc = decay[col];
        float xv[2][4];
#pragma unroll
        for (int mf = 0; mf < 2; ++mf)
#pragma unroll
            for (int j = 0; j < 4; ++j)
                xv[mf][j] = x[(size_t)(row0 + mf * 16 + 4 * hk + j) * DH + col];

        // ---- GEMM1: acc1 = u @ B-chunk (wave cols = (ct*4+w)*16 .. +16)
        f32x4 acc1[2];
        acc1[0] = (f32x4){0.f, 0.f, 0.f, 0.f};
        acc1[1] = (f32x4){0.f, 0.f, 0.f, 0.f};
#pragma unroll
        for (int ks = 0; ks < 4; ++ks) {
            const int ko = ks * 32 + hk * 8;
            s16x8 ah[2], al[2];
#pragma unroll
            for (int mf = 0; mf < 2; ++mf) {
                const int r = mf * 16 + cl;
                const int byte = (r * 256 + ko * 2) ^ ((r & 7) << 4);
                ah[mf] = *(const s16x8*)((const char*)Ah + byte);
                al[mf] = *(const s16x8*)((const char*)Al + byte);
            }
            const size_t fB = (size_t)((ct * 4 + w) * 4 + ks) * 512 + lane * 8;
            s16x8 bh = *(const s16x8*)(bhi + fB);
            s16x8 bl = *(const s16x8*)(blo + fB);
#pragma unroll
            for (int mf = 0; mf < 2; ++mf) acc1[mf] = mfma16(ah[mf], bh, acc1[mf]);
#pragma unroll
            for (int mf = 0; mf < 2; ++mf) acc1[mf] = mfma16(ah[mf], bl, acc1[mf]);
#pragma unroll
            for (int mf = 0; mf < 2; ++mf) acc1[mf] = mfma16(al[mf], bh, acc1[mf]);
        }

        // ---- xn store = acc1 + dv*x
#pragma unroll
        for (int mf = 0; mf < 2; ++mf)
#pragma unroll
            for (int j = 0; j < 4; ++j)
                xn[(size_t)(row0 + mf * 16 + 4 * hk + j) * DH + col] =
                    acc1[mf][j] + dvc * xv[mf][j];

        // ---- GEMM2: acc2 += (decay*x) @ C-chunk; X-frags built in registers
#pragma unroll
        for (int ks2 = 0; ks2 < 2; ++ks2) {
            const int k0 = ct * 64 + ks2 * 32 + hk * 8;
            const f32x4 d0 = *(const f32x4*)&decay[k0];
            const f32x4 d1 = *(const f32x4*)&decay[k0 + 4];
            s16x8 xh[2], xl[2];
#pragma unroll
            for (int mf = 0; mf < 2; ++mf) {
                const float* src = x + (size_t)(row0 + mf * 16 + cl) * DH + k0;
                f32x4 v0 = *(const f32x4*)src * d0;
                f32x4 v1 = *(const f32x4*)(src + 4) * d1;
                Split8 s = split8(v0, v1);
                xh[mf] = s.h;
                xl[mf] = s.l;
            }
            const int ksg = ct * 2 + ks2;
#pragma unroll
            for (int nf2 = 0; nf2 < 2; ++nf2) {
                const size_t fC = (size_t)((w * 2 + nf2) * 16 + ksg) * 512 + lane * 8;
                s16x8 ch = *(const s16x8*)(chi + fC);
                s16x8 cc = *(const s16x8*)(clo + fC);
#pragma unroll
                for (int mf = 0; mf < 2; ++mf) acc2[mf][nf2] = mfma16(xh[mf], ch, acc2[mf][nf2]);
#pragma unroll
                for (int mf = 0; mf < 2; ++mf) acc2[mf][nf2] = mfma16(xh[mf], cc, acc2[mf][nf2]);
#pragma unroll
                for (int mf = 0; mf < 2; ++mf) acc2[mf][nf2] = mfma16(xl[mf], ch, acc2[mf][nf2]);
            }
        }
    }

    // ---- final: acc2 += u @ bc (K=128, wave out-cols w*32 .. +32)
#pragma unroll
    for (int ks = 0; ks < 4; ++ks) {
        const int ko = ks * 32 + hk * 8;
        s16x8 ah[2], al[2];
#pragma unroll
        for (int mf = 0; mf < 2; ++mf) {
            const int r = mf * 16 + cl;
            const int byte = (r * 256 + ko * 2) ^ ((r & 7) << 4);
            ah[mf] = *(const s16x8*)((const char*)Ah + byte);
            al[mf] = *(const s16x8*)((const char*)Al + byte);
        }
#pragma unroll
        for (int nf2 = 0; nf2 < 2; ++nf2) {
            const size_t fbc = (size_t)((w * 2 + nf2) * 4 + ks) * 512 + lane * 8;
            s16x8 h2 = *(const s16x8*)(bch + fbc);
            s16x8 l2 = *(const s16x8*)(bcl + fbc);
#pragma unroll
            for (int mf = 0; mf < 2; ++mf) acc2[mf][nf2] = mfma16(ah[mf], h2, acc2[mf][nf2]);
#pragma unroll
            for (int mf = 0; mf < 2; ++mf) acc2[mf][nf2] = mfma16(ah[mf], l2, acc2[mf][nf2]);
#pragma unroll
            for (int mf = 0; mf < 2; ++mf) acc2[mf][nf2] = mfma16(al[mf], h2, acc2[mf][nf2]);
        }
    }

    // ---- store out[32 x 128]; wave cols [w*32, +32)
#pragma unroll
    for (int nf2 = 0; nf2 < 2; ++nf2) {
        const int ocol = w * 32 + nf2 * 16 + cl;
#pragma unroll
        for (int mf = 0; mf < 2; ++mf)
#pragma unroll
            for (int j = 0; j < 4; ++j)
                out[(size_t)(row0 + mf * 16 + 4 * hk + j) * DOUT + ocol] =
                    acc2[mf][nf2][j];
    }
}

extern "C" void kernel_launch(void* const* d_in, const int* in_sizes, int n_in,
                              void* d_out, int out_size, void* d_ws, size_t ws_size,
                              hipStream_t stream)
{
    const float* x = (const float*)d_in[0];
    const float* u = (const float*)d_in[1];
    const float* a = (const float*)d_in[2];
    const float* b = (const float*)d_in[3];
    const float* c = (const float*)d_in[4];

    float* xn  = (float*)d_out;                       // [BATCH][DH]
    float* out = xn + (size_t)BATCH * DH;             // [BATCH][DOUT]

    char* ws = (char*)d_ws;
    float*  decay = (float*)ws;                       // 512 f32
    ushort* bhi = (ushort*)(ws + 4096);
    ushort* blo = bhi + 128 * 512;
    ushort* chi = blo + 128 * 512;
    ushort* clo = chi + 512 * 128;
    float*  bcf = (float*)(ws + 4096 + 4 * 131072);   // 64KB
    ushort* bch = (ushort*)(ws + 4096 + 4 * 131072 + 65536);
    ushort* bcl = bch + 128 * 128;

    prep1_kernel<<<dim3(129), dim3(256), 0, stream>>>(a, b, c, decay, bhi, blo, chi, clo, bcf);
    prep2_kernel<<<dim3(8), dim3(256), 0, stream>>>(bcf, bch, bcl);
    rnn_fused<<<dim3(BATCH / ROWS), dim3(256), 0, stream>>>(u, x, decay, bhi, blo, chi, clo, bch, bcl, xn, out);
}

// Round 10
// 148.376 us; speedup vs baseline: 1.9643x; 1.9643x over previous
//
#include <hip/hip_runtime.h>
#include <hip/hip_bf16.h>

#define BATCH 65536
#define DIN   128
#define DH    512
#define DOUT  128
#define ROWS  32

typedef __attribute__((ext_vector_type(4))) float f32x4;
typedef __attribute__((ext_vector_type(8))) short s16x8;

__device__ __forceinline__ ushort f32_to_bf16_rn(float f) {
    uint32_t u = __float_as_uint(f);
    uint32_t r = (u + 0x7FFFu + ((u >> 16) & 1u)) >> 16;
    return (ushort)r;
}
__device__ __forceinline__ float bf16_to_f32(ushort h) {
    return __uint_as_float(((uint32_t)h) << 16);
}
__device__ __forceinline__ f32x4 mfma16(s16x8 a, s16x8 b, f32x4 c) {
    return __builtin_amdgcn_mfma_f32_16x16x32_bf16(a, b, c, 0, 0, 0);
}

struct Split8 { s16x8 h, l; };
__device__ __forceinline__ Split8 split8(f32x4 v0, f32x4 v1) {
    Split8 s;
#pragma unroll
    for (int j = 0; j < 4; ++j) {
        ushort hh = f32_to_bf16_rn(v0[j]);
        s.h[j] = (short)hh;
        s.l[j] = (short)f32_to_bf16_rn(v0[j] - bf16_to_f32(hh));
    }
#pragma unroll
    for (int j = 0; j < 4; ++j) {
        ushort hh = f32_to_bf16_rn(v1[j]);
        s.h[4 + j] = (short)hh;
        s.l[4 + j] = (short)f32_to_bf16_rn(v1[j] - bf16_to_f32(hh));
    }
    return s;
}

// lgkm-only barrier: LDS producer->consumer sync WITHOUT draining VMEM.
// ds_read->MFMA ordering is by SSA data deps (compiler loads), so no
// sched_barrier pinning is needed (rule-18 hazard applies to asm ds_reads).
#define LGKM_BARRIER() \
    asm volatile("s_waitcnt lgkmcnt(0)\n\ts_barrier" ::: "memory")

// ---------------------------------------------------------------------------
// prep1: blk0 softmax; blk1..64 B/C split (verified layout); blk65..128
// bc_f32 = b @ c ([128][128] f32, coalesced on c).
// Fragment-linear layout: perm[(f*64+lane)*8+j] = M[k][col],
// k = ks*32+(lane>>4)*8+j, col = cg*16+(lane&15).
// B: f=cg*4+ks (cg<32). C: f=cg*16+ksg (cg<8, ksg<16).
// ---------------------------------------------------------------------------
__global__ void prep1_kernel(const float* __restrict__ a,
                             const float* __restrict__ b,
                             const float* __restrict__ c,
                             float* __restrict__ decay,
                             ushort* __restrict__ bhi, ushort* __restrict__ blo,
                             ushort* __restrict__ chi, ushort* __restrict__ clo,
                             float* __restrict__ bcf)
{
    const int t = threadIdx.x;
    if (blockIdx.x == 0) {
        __shared__ float red[256];
        float v0 = a[t], v1 = a[t + 256];
        red[t] = fmaxf(v0, v1);
        __syncthreads();
        for (int s = 128; s > 0; s >>= 1) {
            if (t < s) red[t] = fmaxf(red[t], red[t + s]);
            __syncthreads();
        }
        float M = red[0];
        __syncthreads();
        float e0 = expf(v0 - M), e1 = expf(v1 - M);
        red[t] = e0 + e1;
        __syncthreads();
        for (int s = 128; s > 0; s >>= 1) {
            if (t < s) red[t] += red[t + s];
            __syncthreads();
        }
        float S = red[0];
        decay[t]       = e0 / S;
        decay[t + 256] = e1 / S;
    } else if (blockIdx.x <= 64) {
        const int p = (blockIdx.x - 1) * 256 + t;
        const int mtx = p >> 13;
        const int q = p & 8191;
        const int f = q >> 6;
        const int l = q & 63;
        s16x8 hi, lo;
        if (mtx == 0) {
            const int cg = f >> 2, ks = f & 3;
            const int col = cg * 16 + (l & 15);
            const int kbase = ks * 32 + (l >> 4) * 8;
#pragma unroll
            for (int j = 0; j < 8; ++j) {
                float v = b[(size_t)(kbase + j) * DH + col];
                ushort h = f32_to_bf16_rn(v);
                hi[j] = (short)h;
                lo[j] = (short)f32_to_bf16_rn(v - bf16_to_f32(h));
            }
            *(s16x8*)(bhi + (size_t)q * 8) = hi;
            *(s16x8*)(blo + (size_t)q * 8) = lo;
        } else {
            const int cg = f >> 4, ks = f & 15;
            const int col = cg * 16 + (l & 15);
            const int kbase = ks * 32 + (l >> 4) * 8;
#pragma unroll
            for (int j = 0; j < 8; ++j) {
                float v = c[(size_t)(kbase + j) * DOUT + col];
                ushort h = f32_to_bf16_rn(v);
                hi[j] = (short)h;
                lo[j] = (short)f32_to_bf16_rn(v - bf16_to_f32(h));
            }
            *(s16x8*)(chi + (size_t)q * 8) = hi;
            *(s16x8*)(clo + (size_t)q * 8) = lo;
        }
    } else {
        // bc = b @ c (f32). One output per thread; c reads coalesced.
        const int i = (blockIdx.x - 65) * 2 + (t >> 7);
        const int j = t & 127;
        float acc = 0.f;
        for (int k = 0; k < DH; ++k)
            acc = fmaf(b[(size_t)i * DH + k], c[(size_t)k * DOUT + j], acc);
        bcf[i * DOUT + j] = acc;
    }
}

// ---------------------------------------------------------------------------
// prep2: split bc_f32 into frag-linear hi/lo (K=128: f = cg*4+ks, cg<8).
// ---------------------------------------------------------------------------
__global__ void prep2_kernel(const float* __restrict__ bcf,
                             ushort* __restrict__ bch, ushort* __restrict__ bcl)
{
    const int p = blockIdx.x * 256 + threadIdx.x;   // [0, 2048)
    const int f = p >> 6, l = p & 63;
    const int cg = f >> 2, ks = f & 3;
    const int col = cg * 16 + (l & 15);
    const int kbase = ks * 32 + (l >> 4) * 8;
    s16x8 hi, lo;
#pragma unroll
    for (int j = 0; j < 8; ++j) {
        float v = bcf[(size_t)(kbase + j) * DOUT + col];
        ushort h = f32_to_bf16_rn(v);
        hi[j] = (short)h;
        lo[j] = (short)f32_to_bf16_rn(v - bf16_to_f32(h));
    }
    *(s16x8*)(bch + (size_t)p * 8) = hi;
    *(s16x8*)(bcl + (size_t)p * 8) = lo;
}

// ---------------------------------------------------------------------------
// fused v6: R5 skeleton + bc-algebra + lgkm-only barriers (1/chunk).
//   xn = u@b + decay*x ; out = (decay*x)@c + u@bc.
// Block 32 rows, 4 waves, 8 chunks x 64 cols. LDS 32KB: A(u) 16KB + X dbuf
// 2x8KB. Per chunk: write X=split(dv*x) from this chunk's x regs (C/D->A
// transpose via LDS, coalesced patterns only), prefetch next x, LGKM_BARRIER,
// GEMM1 48 MFMA (B L2), GEMM2 24 MFMA (X LDS, C L2), xn store (never
// drained: no vmcnt(0) anywhere in the loop). Final u@bc 48 MFMA + out.
// ---------------------------------------------------------------------------
__global__ __launch_bounds__(256, 4)
void rnn_fused(const float* __restrict__ u, const float* __restrict__ x,
               const float* __restrict__ decay,
               const ushort* __restrict__ bhi, const ushort* __restrict__ blo,
               const ushort* __restrict__ chi, const ushort* __restrict__ clo,
               const ushort* __restrict__ bch, const ushort* __restrict__ bcl,
               float* __restrict__ xn, float* __restrict__ out)
{
    __shared__ __align__(16) char smem[32768];
    ushort* Ah = (ushort*)smem;              // [32][128] bf16 hi, swz, 8KB
    ushort* Al = (ushort*)(smem + 8192);

    const int t = threadIdx.x;
    const int lane = t & 63, w = t >> 6;
    const int cl = lane & 15, hk = lane >> 4;
    const int row0 = blockIdx.x * ROWS;

    {   // stage A: u[32][128] f32 -> hi/lo bf16 swizzled, coalesced
        const int r = t >> 3;
        const int kb = (t & 7) * 2;
#pragma unroll
        for (int i = 0; i < 2; ++i) {
            const float* src = u + (size_t)(row0 + r) * DIN + (kb + i) * 8;
            f32x4 v0 = *(const f32x4*)src;
            f32x4 v1 = *(const f32x4*)(src + 4);
            Split8 s = split8(v0, v1);
            const int byte = (r * 256 + (kb + i) * 16) ^ ((r & 7) << 4);
            *(s16x8*)((char*)Ah + byte) = s.h;
            *(s16x8*)((char*)Al + byte) = s.l;
        }
    }

    // prologue: x + decay for chunk 0 (C/D layout: col=w*16+cl, rows via hk,j)
    float xv[2][4], xvn[2][4], dvc, dvn;
    dvc = decay[w * 16 + cl];
#pragma unroll
    for (int mf = 0; mf < 2; ++mf)
#pragma unroll
        for (int j = 0; j < 4; ++j)
            xv[mf][j] = x[(size_t)(row0 + mf * 16 + 4 * hk + j) * DH + w * 16 + cl];

    __syncthreads();   // A + chunk-0 x ready (single full barrier)

    f32x4 acc2[2][2];
#pragma unroll
    for (int mf = 0; mf < 2; ++mf)
#pragma unroll
        for (int nf = 0; nf < 2; ++nf)
            acc2[mf][nf] = (f32x4){0.f, 0.f, 0.f, 0.f};

    for (int ct = 0; ct < 8; ++ct) {
        char* Xh = smem + 16384 + (ct & 1) * 8192;   // [32][64] swz, 4KB
        char* Xl = Xh + 4096;

        // ---- prefetch next chunk's x + decay (stays in flight, no drain)
        if (ct < 7) {
            const int ncol = (ct + 1) * 64 + w * 16 + cl;
            dvn = decay[ncol];
#pragma unroll
            for (int mf = 0; mf < 2; ++mf)
#pragma unroll
                for (int j = 0; j < 4; ++j)
                    xvn[mf][j] = x[(size_t)(row0 + mf * 16 + 4 * hk + j) * DH + ncol];
        }

        // ---- write X = split(dv*x): C/D layout -> A-frag layout transpose
#pragma unroll
        for (int mf = 0; mf < 2; ++mf) {
#pragma unroll
            for (int j = 0; j < 4; ++j) {
                const float v = dvc * xv[mf][j];
                const ushort hh = f32_to_bf16_rn(v);
                const ushort ll = f32_to_bf16_rn(v - bf16_to_f32(hh));
                const int lrow = mf * 16 + 4 * hk + j;
                const int cb = (lrow * 128 + (w * 16 + cl) * 2) ^ ((lrow & 7) << 4);
                *(ushort*)(Xh + cb) = hh;
                *(ushort*)(Xl + cb) = ll;
            }
        }

        LGKM_BARRIER();   // X visible; VMEM (x prefetch, xn stores) in flight

        // ---- GEMM1: acc1 = u @ B-chunk (wave cols = (ct*4+w)*16 .. +16)
        f32x4 acc1[2];
        acc1[0] = (f32x4){0.f, 0.f, 0.f, 0.f};
        acc1[1] = (f32x4){0.f, 0.f, 0.f, 0.f};
#pragma unroll
        for (int ks = 0; ks < 4; ++ks) {
            const int ko = ks * 32 + hk * 8;
            s16x8 ah[2], al[2];
#pragma unroll
            for (int mf = 0; mf < 2; ++mf) {
                const int r = mf * 16 + cl;
                const int byte = (r * 256 + ko * 2) ^ ((r & 7) << 4);
                ah[mf] = *(const s16x8*)((const char*)Ah + byte);
                al[mf] = *(const s16x8*)((const char*)Al + byte);
            }
            const size_t fB = (size_t)((ct * 4 + w) * 4 + ks) * 512 + lane * 8;
            s16x8 bh = *(const s16x8*)(bhi + fB);
            s16x8 bl = *(const s16x8*)(blo + fB);
#pragma unroll
            for (int mf = 0; mf < 2; ++mf) acc1[mf] = mfma16(ah[mf], bh, acc1[mf]);
#pragma unroll
            for (int mf = 0; mf < 2; ++mf) acc1[mf] = mfma16(ah[mf], bl, acc1[mf]);
#pragma unroll
            for (int mf = 0; mf < 2; ++mf) acc1[mf] = mfma16(al[mf], bh, acc1[mf]);
        }

        // ---- GEMM2: acc2 += X @ C-chunk (K=64, ksg = ct*2+ks2)
#pragma unroll
        for (int ks2 = 0; ks2 < 2; ++ks2) {
            s16x8 xh[2], xl[2];
#pragma unroll
            for (int mf = 0; mf < 2; ++mf) {
                const int lrow = mf * 16 + cl;
                const int cb = (lrow * 128 + (ks2 * 32 + hk * 8) * 2) ^ ((lrow & 7) << 4);
                xh[mf] = *(const s16x8*)(Xh + cb);
                xl[mf] = *(const s16x8*)(Xl + cb);
            }
            const int ksg = ct * 2 + ks2;
#pragma unroll
            for (int nf2 = 0; nf2 < 2; ++nf2) {
                const size_t fC = (size_t)((w * 2 + nf2) * 16 + ksg) * 512 + lane * 8;
                s16x8 ch = *(const s16x8*)(chi + fC);
                s16x8 cc = *(const s16x8*)(clo + fC);
#pragma unroll
                for (int mf = 0; mf < 2; ++mf) acc2[mf][nf2] = mfma16(xh[mf], ch, acc2[mf][nf2]);
#pragma unroll
                for (int mf = 0; mf < 2; ++mf) acc2[mf][nf2] = mfma16(xh[mf], cc, acc2[mf][nf2]);
#pragma unroll
                for (int mf = 0; mf < 2; ++mf) acc2[mf][nf2] = mfma16(xl[mf], ch, acc2[mf][nf2]);
            }
        }

        // ---- xn store = acc1 + dv*x (free-flowing, never drained)
        {
            const int col = ct * 64 + w * 16 + cl;
#pragma unroll
            for (int mf = 0; mf < 2; ++mf)
#pragma unroll
                for (int j = 0; j < 4; ++j)
                    xn[(size_t)(row0 + mf * 16 + 4 * hk + j) * DH + col] =
                        acc1[mf][j] + dvc * xv[mf][j];
        }

        // rotate x prefetch
        dvc = dvn;
#pragma unroll
        for (int mf = 0; mf < 2; ++mf)
#pragma unroll
            for (int j = 0; j < 4; ++j) xv[mf][j] = xvn[mf][j];
    }

    // ---- final: acc2 += u @ bc (K=128, wave out-cols w*32 .. +32)
#pragma unroll
    for (int ks = 0; ks < 4; ++ks) {
        const int ko = ks * 32 + hk * 8;
        s16x8 ah[2], al[2];
#pragma unroll
        for (int mf = 0; mf < 2; ++mf) {
            const int r = mf * 16 + cl;
            const int byte = (r * 256 + ko * 2) ^ ((r & 7) << 4);
            ah[mf] = *(const s16x8*)((const char*)Ah + byte);
            al[mf] = *(const s16x8*)((const char*)Al + byte);
        }
#pragma unroll
        for (int nf2 = 0; nf2 < 2; ++nf2) {
            const size_t fbc = (size_t)((w * 2 + nf2) * 4 + ks) * 512 + lane * 8;
            s16x8 h2 = *(const s16x8*)(bch + fbc);
            s16x8 l2 = *(const s16x8*)(bcl + fbc);
#pragma unroll
            for (int mf = 0; mf < 2; ++mf) acc2[mf][nf2] = mfma16(ah[mf], h2, acc2[mf][nf2]);
#pragma unroll
            for (int mf = 0; mf < 2; ++mf) acc2[mf][nf2] = mfma16(ah[mf], l2, acc2[mf][nf2]);
#pragma unroll
            for (int mf = 0; mf < 2; ++mf) acc2[mf][nf2] = mfma16(al[mf], h2, acc2[mf][nf2]);
        }
    }

    // ---- store out[32 x 128]; wave cols [w*32, +32)
#pragma unroll
    for (int nf2 = 0; nf2 < 2; ++nf2) {
        const int ocol = w * 32 + nf2 * 16 + cl;
#pragma unroll
        for (int mf = 0; mf < 2; ++mf)
#pragma unroll
            for (int j = 0; j < 4; ++j)
                out[(size_t)(row0 + mf * 16 + 4 * hk + j) * DOUT + ocol] =
                    acc2[mf][nf2][j];
    }
}

extern "C" void kernel_launch(void* const* d_in, const int* in_sizes, int n_in,
                              void* d_out, int out_size, void* d_ws, size_t ws_size,
                              hipStream_t stream)
{
    const float* x = (const float*)d_in[0];
    const float* u = (const float*)d_in[1];
    const float* a = (const float*)d_in[2];
    const float* b = (const float*)d_in[3];
    const float* c = (const float*)d_in[4];

    float* xn  = (float*)d_out;                       // [BATCH][DH]
    float* out = xn + (size_t)BATCH * DH;             // [BATCH][DOUT]

    char* ws = (char*)d_ws;
    float*  decay = (float*)ws;                       // 512 f32
    ushort* bhi = (ushort*)(ws + 4096);
    ushort* blo = bhi + 128 * 512;
    ushort* chi = blo + 128 * 512;
    ushort* clo = chi + 512 * 128;
    float*  bcf = (float*)(ws + 4096 + 4 * 131072);   // 64KB
    ushort* bch = (ushort*)(ws + 4096 + 4 * 131072 + 65536);
    ushort* bcl = bch + 128 * 128;

    prep1_kernel<<<dim3(129), dim3(256), 0, stream>>>(a, b, c, decay, bhi, blo, chi, clo, bcf);
    prep2_kernel<<<dim3(8), dim3(256), 0, stream>>>(bcf, bch, bcl);
    rnn_fused<<<dim3(BATCH / ROWS), dim3(256), 0, stream>>>(u, x, decay, bhi, blo, chi, clo, bch, bcl, xn, out);
}

// Round 11
// 129.187 us; speedup vs baseline: 2.2561x; 1.1485x over previous
//
#include <hip/hip_runtime.h>
#include <hip/hip_bf16.h>

#define BATCH 65536
#define DIN   128
#define DH    512
#define DOUT  128
#define ROWS  32

typedef __attribute__((ext_vector_type(4))) float f32x4;
typedef __attribute__((ext_vector_type(8))) short s16x8;

__device__ __forceinline__ ushort f32_to_bf16_rn(float f) {
    uint32_t u = __float_as_uint(f);
    uint32_t r = (u + 0x7FFFu + ((u >> 16) & 1u)) >> 16;
    return (ushort)r;
}
__device__ __forceinline__ float bf16_to_f32(ushort h) {
    return __uint_as_float(((uint32_t)h) << 16);
}
__device__ __forceinline__ f32x4 mfma16(s16x8 a, s16x8 b, f32x4 c) {
    return __builtin_amdgcn_mfma_f32_16x16x32_bf16(a, b, c, 0, 0, 0);
}

struct Split8 { s16x8 h, l; };
__device__ __forceinline__ Split8 split8(f32x4 v0, f32x4 v1) {
    Split8 s;
#pragma unroll
    for (int j = 0; j < 4; ++j) {
        ushort hh = f32_to_bf16_rn(v0[j]);
        s.h[j] = (short)hh;
        s.l[j] = (short)f32_to_bf16_rn(v0[j] - bf16_to_f32(hh));
    }
#pragma unroll
    for (int j = 0; j < 4; ++j) {
        ushort hh = f32_to_bf16_rn(v1[j]);
        s.h[4 + j] = (short)hh;
        s.l[4 + j] = (short)f32_to_bf16_rn(v1[j] - bf16_to_f32(hh));
    }
    return s;
}

// ---------------------------------------------------------------------------
// prep1: blk0 softmax; blk1..64 B/C split (verified layout); blk65..128
// bc_f32 = b @ c ([128][128] f32, coalesced on c).
// Fragment-linear layout: perm[(f*64+lane)*8+j] = M[k][col],
// k = ks*32+(lane>>4)*8+j, col = cg*16+(lane&15).
// B: f=cg*4+ks (cg<32). C: f=cg*16+ksg (cg<8, ksg<16).
// ---------------------------------------------------------------------------
__global__ void prep1_kernel(const float* __restrict__ a,
                             const float* __restrict__ b,
                             const float* __restrict__ c,
                             float* __restrict__ decay,
                             ushort* __restrict__ bhi, ushort* __restrict__ blo,
                             ushort* __restrict__ chi, ushort* __restrict__ clo,
                             float* __restrict__ bcf)
{
    const int t = threadIdx.x;
    if (blockIdx.x == 0) {
        __shared__ float red[256];
        float v0 = a[t], v1 = a[t + 256];
        red[t] = fmaxf(v0, v1);
        __syncthreads();
        for (int s = 128; s > 0; s >>= 1) {
            if (t < s) red[t] = fmaxf(red[t], red[t + s]);
            __syncthreads();
        }
        float M = red[0];
        __syncthreads();
        float e0 = expf(v0 - M), e1 = expf(v1 - M);
        red[t] = e0 + e1;
        __syncthreads();
        for (int s = 128; s > 0; s >>= 1) {
            if (t < s) red[t] += red[t + s];
            __syncthreads();
        }
        float S = red[0];
        decay[t]       = e0 / S;
        decay[t + 256] = e1 / S;
    } else if (blockIdx.x <= 64) {
        const int p = (blockIdx.x - 1) * 256 + t;
        const int mtx = p >> 13;
        const int q = p & 8191;
        const int f = q >> 6;
        const int l = q & 63;
        s16x8 hi, lo;
        if (mtx == 0) {
            const int cg = f >> 2, ks = f & 3;
            const int col = cg * 16 + (l & 15);
            const int kbase = ks * 32 + (l >> 4) * 8;
#pragma unroll
            for (int j = 0; j < 8; ++j) {
                float v = b[(size_t)(kbase + j) * DH + col];
                ushort h = f32_to_bf16_rn(v);
                hi[j] = (short)h;
                lo[j] = (short)f32_to_bf16_rn(v - bf16_to_f32(h));
            }
            *(s16x8*)(bhi + (size_t)q * 8) = hi;
            *(s16x8*)(blo + (size_t)q * 8) = lo;
        } else {
            const int cg = f >> 4, ks = f & 15;
            const int col = cg * 16 + (l & 15);
            const int kbase = ks * 32 + (l >> 4) * 8;
#pragma unroll
            for (int j = 0; j < 8; ++j) {
                float v = c[(size_t)(kbase + j) * DOUT + col];
                ushort h = f32_to_bf16_rn(v);
                hi[j] = (short)h;
                lo[j] = (short)f32_to_bf16_rn(v - bf16_to_f32(h));
            }
            *(s16x8*)(chi + (size_t)q * 8) = hi;
            *(s16x8*)(clo + (size_t)q * 8) = lo;
        }
    } else {
        // bc = b @ c (f32). One output per thread; c reads coalesced.
        const int i = (blockIdx.x - 65) * 2 + (t >> 7);
        const int j = t & 127;
        float acc = 0.f;
        for (int k = 0; k < DH; ++k)
            acc = fmaf(b[(size_t)i * DH + k], c[(size_t)k * DOUT + j], acc);
        bcf[i * DOUT + j] = acc;
    }
}

// ---------------------------------------------------------------------------
// prep2: split bc_f32 into frag-linear hi/lo (K=128: f = cg*4+ks, cg<8).
// ---------------------------------------------------------------------------
__global__ void prep2_kernel(const float* __restrict__ bcf,
                             ushort* __restrict__ bch, ushort* __restrict__ bcl)
{
    const int p = blockIdx.x * 256 + threadIdx.x;   // [0, 2048)
    const int f = p >> 6, l = p & 63;
    const int cg = f >> 2, ks = f & 3;
    const int col = cg * 16 + (l & 15);
    const int kbase = ks * 32 + (l >> 4) * 8;
    s16x8 hi, lo;
#pragma unroll
    for (int j = 0; j < 8; ++j) {
        float v = bcf[(size_t)(kbase + j) * DOUT + col];
        ushort h = f32_to_bf16_rn(v);
        hi[j] = (short)h;
        lo[j] = (short)f32_to_bf16_rn(v - bf16_to_f32(h));
    }
    *(s16x8*)(bch + (size_t)p * 8) = hi;
    *(s16x8*)(bcl + (size_t)p * 8) = lo;
}

// ---------------------------------------------------------------------------
// fused v7: bc-algebra + single barrier/chunk + fully-coalesced x staging.
//   xn = u@b + decay*x ; out = (decay*x)@c + u@bc.
// Block 32 rows, 4 waves, 8 chunks x 64 cols. LDS 32KB: A(u) 16KB + X dbuf
// 2x8KB -> 5 blocks/CU. Per chunk:
//   stage X[ct&1] = split(decay*x) from regs (64B/thread coalesced loads,
//     prefetched one chunk ahead) -> __syncthreads (the ONLY barrier) ->
//   merged region: GEMM1 (u@B, 24 MFMA, B-frags L2) ; xn = acc1 + (Xh+Xl)
//     read back from LDS (no 2nd global x read) ; GEMM2 (X@C, 24 MFMA).
// Final: acc2 += u@bc (48 MFMA), out store. 8 barriers/block total.
// ---------------------------------------------------------------------------
__global__ __launch_bounds__(256, 4)
void rnn_fused(const float* __restrict__ u, const float* __restrict__ x,
               const float* __restrict__ decay,
               const ushort* __restrict__ bhi, const ushort* __restrict__ blo,
               const ushort* __restrict__ chi, const ushort* __restrict__ clo,
               const ushort* __restrict__ bch, const ushort* __restrict__ bcl,
               float* __restrict__ xn, float* __restrict__ out)
{
    __shared__ __align__(16) char smem[32768];
    ushort* Ah = (ushort*)smem;              // [32][128] bf16 hi, swz, 8KB
    ushort* Al = (ushort*)(smem + 8192);

    const int t = threadIdx.x;
    const int lane = t & 63, w = t >> 6;
    const int cl = lane & 15, hk = lane >> 4;
    const int row0 = blockIdx.x * ROWS;

    {   // stage A: u[32][128] f32 -> hi/lo bf16 swizzled, coalesced
        const int r = t >> 3;
        const int kb = (t & 7) * 2;
#pragma unroll
        for (int i = 0; i < 2; ++i) {
            const float* src = u + (size_t)(row0 + r) * DIN + (kb + i) * 8;
            f32x4 v0 = *(const f32x4*)src;
            f32x4 v1 = *(const f32x4*)(src + 4);
            Split8 s = split8(v0, v1);
            const int byte = (r * 256 + (kb + i) * 16) ^ ((r & 7) << 4);
            *(s16x8*)((char*)Ah + byte) = s.h;
            *(s16x8*)((char*)Al + byte) = s.l;
        }
    }

    // x staging geometry: thread covers row sr, cols [skb*8, skb*8+8) of chunk
    const int sr = t >> 3, skb = t & 7;
    const float* xrow = x + (size_t)(row0 + sr) * DH + skb * 8;

    // prologue: prefetch chunk-0 x
    f32x4 xr0 = *(const f32x4*)xrow;
    f32x4 xr1 = *(const f32x4*)(xrow + 4);

    f32x4 acc2[2][2];
#pragma unroll
    for (int mf = 0; mf < 2; ++mf)
#pragma unroll
        for (int nf = 0; nf < 2; ++nf)
            acc2[mf][nf] = (f32x4){0.f, 0.f, 0.f, 0.f};

    for (int ct = 0; ct < 8; ++ct) {
        char* Xh = smem + 16384 + (ct & 1) * 8192;   // [32][64] bf16, swz, 4KB
        char* Xl = Xh + 4096;

        // ---- stage X = split(decay * x) from prefetched regs (pure VALU+LDS)
        {
            const f32x4 d0 = *(const f32x4*)&decay[ct * 64 + skb * 8];
            const f32x4 d1 = *(const f32x4*)&decay[ct * 64 + skb * 8 + 4];
            Split8 s = split8(xr0 * d0, xr1 * d1);
            const int sbyte = (sr * 128 + skb * 16) ^ ((sr & 7) << 4);
            *(s16x8*)(Xh + sbyte) = s.h;
            *(s16x8*)(Xl + sbyte) = s.l;
        }

        // ---- prefetch next chunk's x (in flight across barrier + compute)
        if (ct < 7) {
            xr0 = *(const f32x4*)(xrow + (ct + 1) * 64);
            xr1 = *(const f32x4*)(xrow + (ct + 1) * 64 + 4);
        }

        __syncthreads();   // A (first iter) + X[ct&1] visible

        // ---- GEMM1: acc1 = u @ B-chunk (wave cols = (ct*4+w)*16 .. +16)
        f32x4 acc1[2];
        acc1[0] = (f32x4){0.f, 0.f, 0.f, 0.f};
        acc1[1] = (f32x4){0.f, 0.f, 0.f, 0.f};
#pragma unroll
        for (int ks = 0; ks < 4; ++ks) {
            const int ko = ks * 32 + hk * 8;
            s16x8 ah[2], al[2];
#pragma unroll
            for (int mf = 0; mf < 2; ++mf) {
                const int r = mf * 16 + cl;
                const int byte = (r * 256 + ko * 2) ^ ((r & 7) << 4);
                ah[mf] = *(const s16x8*)((const char*)Ah + byte);
                al[mf] = *(const s16x8*)((const char*)Al + byte);
            }
            const size_t fB = (size_t)((ct * 4 + w) * 4 + ks) * 512 + lane * 8;
            s16x8 bh = *(const s16x8*)(bhi + fB);
            s16x8 bl = *(const s16x8*)(blo + fB);
#pragma unroll
            for (int mf = 0; mf < 2; ++mf) acc1[mf] = mfma16(ah[mf], bh, acc1[mf]);
#pragma unroll
            for (int mf = 0; mf < 2; ++mf) acc1[mf] = mfma16(ah[mf], bl, acc1[mf]);
#pragma unroll
            for (int mf = 0; mf < 2; ++mf) acc1[mf] = mfma16(al[mf], bh, acc1[mf]);
        }

        // ---- xn = acc1 + (dv*x) recombined from X LDS (C/D positions)
        {
            const int col = ct * 64 + w * 16 + cl;
#pragma unroll
            for (int mf = 0; mf < 2; ++mf) {
#pragma unroll
                for (int j = 0; j < 4; ++j) {
                    const int lrow = mf * 16 + 4 * hk + j;
                    const int cb = (lrow * 128 + (w * 16 + cl) * 2) ^ ((lrow & 7) << 4);
                    const float dvx = bf16_to_f32(*(const ushort*)(Xh + cb)) +
                                      bf16_to_f32(*(const ushort*)(Xl + cb));
                    xn[(size_t)(row0 + lrow) * DH + col] = acc1[mf][j] + dvx;
                }
            }
        }

        // ---- GEMM2: acc2 += X @ C-chunk (K=64, ksg = ct*2+ks2)
#pragma unroll
        for (int ks2 = 0; ks2 < 2; ++ks2) {
            s16x8 xh[2], xl[2];
#pragma unroll
            for (int mf = 0; mf < 2; ++mf) {
                const int lrow = mf * 16 + cl;
                const int cb = (lrow * 128 + (ks2 * 32 + hk * 8) * 2) ^ ((lrow & 7) << 4);
                xh[mf] = *(const s16x8*)(Xh + cb);
                xl[mf] = *(const s16x8*)(Xl + cb);
            }
            const int ksg = ct * 2 + ks2;
#pragma unroll
            for (int nf2 = 0; nf2 < 2; ++nf2) {
                const size_t fC = (size_t)((w * 2 + nf2) * 16 + ksg) * 512 + lane * 8;
                s16x8 ch = *(const s16x8*)(chi + fC);
                s16x8 cc = *(const s16x8*)(clo + fC);
#pragma unroll
                for (int mf = 0; mf < 2; ++mf) acc2[mf][nf2] = mfma16(xh[mf], ch, acc2[mf][nf2]);
#pragma unroll
                for (int mf = 0; mf < 2; ++mf) acc2[mf][nf2] = mfma16(xh[mf], cc, acc2[mf][nf2]);
#pragma unroll
                for (int mf = 0; mf < 2; ++mf) acc2[mf][nf2] = mfma16(xl[mf], ch, acc2[mf][nf2]);
            }
        }
    }

    // ---- final: acc2 += u @ bc (K=128, wave out-cols w*32 .. +32)
#pragma unroll
    for (int ks = 0; ks < 4; ++ks) {
        const int ko = ks * 32 + hk * 8;
        s16x8 ah[2], al[2];
#pragma unroll
        for (int mf = 0; mf < 2; ++mf) {
            const int r = mf * 16 + cl;
            const int byte = (r * 256 + ko * 2) ^ ((r & 7) << 4);
            ah[mf] = *(const s16x8*)((const char*)Ah + byte);
            al[mf] = *(const s16x8*)((const char*)Al + byte);
        }
#pragma unroll
        for (int nf2 = 0; nf2 < 2; ++nf2) {
            const size_t fbc = (size_t)((w * 2 + nf2) * 4 + ks) * 512 + lane * 8;
            s16x8 h2 = *(const s16x8*)(bch + fbc);
            s16x8 l2 = *(const s16x8*)(bcl + fbc);
#pragma unroll
            for (int mf = 0; mf < 2; ++mf) acc2[mf][nf2] = mfma16(ah[mf], h2, acc2[mf][nf2]);
#pragma unroll
            for (int mf = 0; mf < 2; ++mf) acc2[mf][nf2] = mfma16(ah[mf], l2, acc2[mf][nf2]);
#pragma unroll
            for (int mf = 0; mf < 2; ++mf) acc2[mf][nf2] = mfma16(al[mf], h2, acc2[mf][nf2]);
        }
    }

    // ---- store out[32 x 128]; wave cols [w*32, +32)
#pragma unroll
    for (int nf2 = 0; nf2 < 2; ++nf2) {
        const int ocol = w * 32 + nf2 * 16 + cl;
#pragma unroll
        for (int mf = 0; mf < 2; ++mf)
#pragma unroll
            for (int j = 0; j < 4; ++j)
                out[(size_t)(row0 + mf * 16 + 4 * hk + j) * DOUT + ocol] =
                    acc2[mf][nf2][j];
    }
}

extern "C" void kernel_launch(void* const* d_in, const int* in_sizes, int n_in,
                              void* d_out, int out_size, void* d_ws, size_t ws_size,
                              hipStream_t stream)
{
    const float* x = (const float*)d_in[0];
    const float* u = (const float*)d_in[1];
    const float* a = (const float*)d_in[2];
    const float* b = (const float*)d_in[3];
    const float* c = (const float*)d_in[4];

    float* xn  = (float*)d_out;                       // [BATCH][DH]
    float* out = xn + (size_t)BATCH * DH;             // [BATCH][DOUT]

    char* ws = (char*)d_ws;
    float*  decay = (float*)ws;                       // 512 f32
    ushort* bhi = (ushort*)(ws + 4096);
    ushort* blo = bhi + 128 * 512;
    ushort* chi = blo + 128 * 512;
    ushort* clo = chi + 512 * 128;
    float*  bcf = (float*)(ws + 4096 + 4 * 131072);   // 64KB
    ushort* bch = (ushort*)(ws + 4096 + 4 * 131072 + 65536);
    ushort* bcl = bch + 128 * 128;

    prep1_kernel<<<dim3(129), dim3(256), 0, stream>>>(a, b, c, decay, bhi, blo, chi, clo, bcf);
    prep2_kernel<<<dim3(8), dim3(256), 0, stream>>>(bcf, bch, bcl);
    rnn_fused<<<dim3(BATCH / ROWS), dim3(256), 0, stream>>>(u, x, decay, bhi, blo, chi, clo, bch, bcl, xn, out);
}